// Round 2
// baseline (625.665 us; speedup 1.0000x reference)
//
#include <hip/hip_runtime.h>
#include <hip/hip_bf16.h>

#define NTOK 49
#define DIM 192
#define NHEAD 6
#define HD 32
#define SCALE_F 0.1767766952966369f  // 32^-0.5

typedef __attribute__((ext_vector_type(8))) short bf16x8;
typedef __attribute__((ext_vector_type(4))) float f32x4;

__device__ __forceinline__ unsigned short f2bf(float f) {
    unsigned int u = __float_as_uint(f);
    unsigned int r = (u + 0x7FFF + ((u >> 16) & 1)) >> 16;  // RNE (finite inputs)
    return (unsigned short)r;
}
__device__ __forceinline__ float bf2f(unsigned short h) {
    return __uint_as_float(((unsigned int)h) << 16);
}

// ---- LDS layout (ushort/bf16 elements unless noted) ----
#define SX_STRIDE 200                 // 64 rows of x / O; 400B rows -> 2-way bank alias (free)
#define SX_ELEMS (64 * 200)           // 12800
#define SQK_STRIDE 40                 // Q,K: 64 rows, 80B rows -> 2-way
#define SP_STRIDE 88                  // P: 64 rows, 176B rows -> 2-way
#define SVT_STRIDE 88                 // Vt: 32 rows
#define K_OFF (64 * 40)               // K after Q
#define VT_OFF (64 * 88)              // P overlays Q+K (5120 < 5632); Vt after
#define ARENA_ELEMS (64 * 88 + 32 * 88)
#define SREL_OFF (SX_ELEMS * 2 + NHEAD * ARENA_ELEMS * 2)  // 126976 B
#define SBIAS_OFF (SREL_OFF + 4804)                        // 131780 B
#define SMEM_BYTES (SBIAS_OFF + 1014 * 4)                  // 135836 B

// ---- workspace layout (bytes) ----
#define WS_FLAG_OFF 0
#define WS_WTQKV_OFF 16
#define WS_WTPROJ_OFF (WS_WTQKV_OFF + 576 * 192 * 2)   // 221200
#define WS_QKVB_OFF (WS_WTPROJ_OFF + 192 * 192 * 2)    // 294928
#define WS_PROJB_OFF (WS_QKVB_OFF + 576 * 4)           // 297232
#define WS_BIAS_OFF (WS_PROJB_OFF + 192 * 4)           // 298000
#define WS_BYTES (WS_BIAS_OFF + 1014 * 4)              // 302056

// Detect whether float inputs are fp32 (flag=1) or bf16 (flag=0).
// bf16 N(0,1) data decodes to |v| <= ~6 for every half-word; fp32 data's low
// half-words decode as garbage exponents -> some |v| >= 1000 or NaN among 128.
__global__ void detect_dtype(const unsigned short* __restrict__ xraw, int* __restrict__ flag) {
    if (threadIdx.x == 0 && blockIdx.x == 0) {
        int bad = 0;
        for (int i = 0; i < 128; ++i) {
            float v = bf2f(xraw[i]);
            if (!(fabsf(v) < 1000.0f)) bad = 1;  // catches NaN too
        }
        *flag = bad;
    }
}

__device__ __forceinline__ float rd_any(const void* p, int i, int is_fp32) {
    return is_fp32 ? ((const float*)p)[i] : bf2f(((const unsigned short*)p)[i]);
}

// Normalize params into ws: transposed bf16 weights + fp32 bias tables.
__global__ void prep_params(const void* __restrict__ qkv_w, const void* __restrict__ proj_w,
                            const void* __restrict__ qkv_b, const void* __restrict__ proj_b,
                            const void* __restrict__ bias_table, char* __restrict__ ws) {
    const int is_fp32 = *(const int*)(ws + WS_FLAG_OFF);
    unsigned short* WtQkv = (unsigned short*)(ws + WS_WTQKV_OFF);
    unsigned short* WtProj = (unsigned short*)(ws + WS_WTPROJ_OFF);
    float* fQkvB = (float*)(ws + WS_QKVB_OFF);
    float* fProjB = (float*)(ws + WS_PROJB_OFF);
    float* fBias = (float*)(ws + WS_BIAS_OFF);

    int t = blockIdx.x * blockDim.x + threadIdx.x;
    if (t < 110592) {                       // WtQkv[n][k] = qkv_w[k][n]
        int n = t / 192, k = t - n * 192;
        WtQkv[t] = f2bf(rd_any(qkv_w, k * 576 + n, is_fp32));
        return;
    }
    int t2 = t - 110592;
    if (t2 < 36864) {                       // WtProj[n][k] = proj_w[k][n]
        int n = t2 / 192, k = t2 - n * 192;
        WtProj[t2] = f2bf(rd_any(proj_w, k * 192 + n, is_fp32));
        return;
    }
    int t3 = t2 - 36864;
    if (t3 < 576) { fQkvB[t3] = rd_any(qkv_b, t3, is_fp32); return; }
    int t4 = t3 - 576;
    if (t4 < 192) { fProjB[t4] = rd_any(proj_b, t4, is_fp32); return; }
    int t5 = t4 - 192;
    if (t5 < 1014) {                        // fBias[h][r] = bias_table[r][h]
        int r = t5 / NHEAD, h = t5 - r * NHEAD;
        fBias[h * 169 + r] = rd_any(bias_table, t5, is_fp32);
    }
}

__global__ __launch_bounds__(384, 2)
void win_attn_fused(const void* __restrict__ X,
                    const int* __restrict__ rel_idx,
                    const char* __restrict__ ws,
                    void* __restrict__ Out) {
    extern __shared__ char smem[];
    unsigned short* sX = (unsigned short*)smem;
    unsigned short* sArenaAll = sX + SX_ELEMS;
    unsigned short* sRel = (unsigned short*)(smem + SREL_OFF);
    float* sBias = (float*)(smem + SBIAS_OFF);

    const unsigned short* WtQkv = (const unsigned short*)(ws + WS_WTQKV_OFF);
    const unsigned short* WtProj = (const unsigned short*)(ws + WS_WTPROJ_OFF);
    const float* fQkvB = (const float*)(ws + WS_QKVB_OFF);
    const float* fProjB = (const float*)(ws + WS_PROJB_OFF);
    const float* fBias = (const float*)(ws + WS_BIAS_OFF);
    const int is_fp32 = *(const int*)(ws + WS_FLAG_OFF);

    const int tid = threadIdx.x;
    const int wv = tid >> 6;       // wave index == head
    const int lane = tid & 63;
    const int l15 = lane & 15;
    const int quad = lane >> 4;
    const int q8 = quad * 8;
    const int q4 = quad * 4;
    const int bw = blockIdx.x;

    // ---------- Phase 0: stage x (-> bf16), rel_idx, bias table ----------
    if (is_fp32) {
        const float* xw = (const float*)X + (size_t)bw * (NTOK * DIM);
        for (int t = tid; t < (NTOK * DIM) / 4; t += 384) {  // 2352 float4
            int e = t * 4;
            int row = e / DIM;
            int col = e - row * DIM;
            float4 v = *(const float4*)(xw + e);
            ushort4 o;
            o.x = f2bf(v.x); o.y = f2bf(v.y); o.z = f2bf(v.z); o.w = f2bf(v.w);
            *(ushort4*)(sX + row * SX_STRIDE + col) = o;
        }
    } else {
        const unsigned short* xw = (const unsigned short*)X + (size_t)bw * (NTOK * DIM);
        for (int t = tid; t < (NTOK * DIM) / 8; t += 384) {  // 1176 vec8
            int e = t * 8;
            int row = e / DIM;
            int col = e - row * DIM;
            *(bf16x8*)(sX + row * SX_STRIDE + col) = *(const bf16x8*)(xw + e);
        }
    }
    {
        bf16x8 z8 = {0, 0, 0, 0, 0, 0, 0, 0};
        for (int t = tid; t < 360; t += 384) {  // zero rows 49..63
            int e = t * 8;
            int row = 49 + e / DIM;
            int col = e % DIM;
            *(bf16x8*)(sX + row * SX_STRIDE + col) = z8;
        }
    }
    for (int t = tid; t < NTOK * NTOK; t += 384) sRel[t] = (unsigned short)rel_idx[t];
    for (int t = tid; t < 169 * NHEAD; t += 384) sBias[t] = fBias[t];
    __syncthreads();

    unsigned short* sQ = sArenaAll + wv * ARENA_ELEMS;
    unsigned short* sK = sQ + K_OFF;
    unsigned short* sP = sQ;   // overlays Q+K after S is done (same wave only)
    unsigned short* sVt = sQ + VT_OFF;

    // ---------- Phase 1: QKV = x @ qkv_w + b (per head: 96 cols) ----------
    f32x4 accQ[4][2], accK[4][2], accV[4][2];
    {
        f32x4 zf = {0.f, 0.f, 0.f, 0.f};
#pragma unroll
        for (int mt = 0; mt < 4; ++mt)
#pragma unroll
            for (int nt = 0; nt < 2; ++nt) { accQ[mt][nt] = zf; accK[mt][nt] = zf; accV[mt][nt] = zf; }
    }
#pragma unroll
    for (int kb = 0; kb < 6; ++kb) {
        const int k0 = kb * 32 + q8;
        bf16x8 afr[4];
#pragma unroll
        for (int mt = 0; mt < 4; ++mt)
            afr[mt] = *(const bf16x8*)(sX + (mt * 16 + l15) * SX_STRIDE + k0);
#pragma unroll
        for (int nt = 0; nt < 2; ++nt) {
            const int n = wv * HD + nt * 16 + l15;
            bf16x8 bq = *(const bf16x8*)(WtQkv + (size_t)n * DIM + k0);
            bf16x8 bk = *(const bf16x8*)(WtQkv + (size_t)(n + DIM) * DIM + k0);
            bf16x8 bv = *(const bf16x8*)(WtQkv + (size_t)(n + 2 * DIM) * DIM + k0);
#pragma unroll
            for (int mt = 0; mt < 4; ++mt) {
                accQ[mt][nt] = __builtin_amdgcn_mfma_f32_16x16x32_bf16(afr[mt], bq, accQ[mt][nt], 0, 0, 0);
                accK[mt][nt] = __builtin_amdgcn_mfma_f32_16x16x32_bf16(afr[mt], bk, accK[mt][nt], 0, 0, 0);
                accV[mt][nt] = __builtin_amdgcn_mfma_f32_16x16x32_bf16(afr[mt], bv, accV[mt][nt], 0, 0, 0);
            }
        }
    }
    // epilogue: +bias, Q*=scale, Q/K row-major, V transposed
#pragma unroll
    for (int nt = 0; nt < 2; ++nt) {
        const int c = wv * HD + nt * 16 + l15;
        const float bq = fQkvB[c], bk2 = fQkvB[c + DIM], bv2 = fQkvB[c + 2 * DIM];
#pragma unroll
        for (int mt = 0; mt < 4; ++mt) {
#pragma unroll
            for (int r = 0; r < 4; ++r) {
                const int row = mt * 16 + q4 + r;
                sQ[row * SQK_STRIDE + nt * 16 + l15] = f2bf((accQ[mt][nt][r] + bq) * SCALE_F);
                sK[row * SQK_STRIDE + nt * 16 + l15] = f2bf(accK[mt][nt][r] + bk2);
                sVt[(nt * 16 + l15) * SVT_STRIDE + row] = f2bf(accV[mt][nt][r] + bv2);
            }
        }
    }
    __syncthreads();  // publishes Q/K/Vt; all sX reads for phase 1 done

    // ---------- Phase 2: S = Q' K^T (+bias), masked softmax, P -> LDS ----------
    f32x4 accS[4][4];
    {
        f32x4 zf = {0.f, 0.f, 0.f, 0.f};
#pragma unroll
        for (int mt = 0; mt < 4; ++mt)
#pragma unroll
            for (int nt = 0; nt < 4; ++nt) accS[mt][nt] = zf;
    }
    {
        bf16x8 aq[4], bkf[4];
#pragma unroll
        for (int mt = 0; mt < 4; ++mt)
            aq[mt] = *(const bf16x8*)(sQ + (mt * 16 + l15) * SQK_STRIDE + q8);
#pragma unroll
        for (int nt = 0; nt < 4; ++nt)
            bkf[nt] = *(const bf16x8*)(sK + (nt * 16 + l15) * SQK_STRIDE + q8);
#pragma unroll
        for (int mt = 0; mt < 4; ++mt)
#pragma unroll
            for (int nt = 0; nt < 4; ++nt)
                accS[mt][nt] = __builtin_amdgcn_mfma_f32_16x16x32_bf16(aq[mt], bkf[nt], accS[mt][nt], 0, 0, 0);
    }
    const float* sBiasH = sBias + wv * 169;
#pragma unroll
    for (int mt = 0; mt < 4; ++mt) {
#pragma unroll
        for (int r = 0; r < 4; ++r) {
            const int m = mt * 16 + q4 + r;
            const int mi = (m < NTOK) ? m : 0;
            float vv[4];
#pragma unroll
            for (int nt = 0; nt < 4; ++nt) {
                const int j = nt * 16 + l15;
                float s = accS[mt][nt][r];
                if (j < NTOK) s += sBiasH[sRel[mi * NTOK + j]];
                else s = -1e9f;
                vv[nt] = s;
            }
            float mx = fmaxf(fmaxf(vv[0], vv[1]), fmaxf(vv[2], vv[3]));
#pragma unroll
            for (int d = 1; d < 16; d <<= 1) mx = fmaxf(mx, __shfl_xor(mx, d, 16));
            float pr[4];
            float sum = 0.f;
#pragma unroll
            for (int nt = 0; nt < 4; ++nt) {
                const int j = nt * 16 + l15;
                const float e = (j < NTOK) ? __expf(vv[nt] - mx) : 0.f;
                pr[nt] = e;
                sum += e;
            }
#pragma unroll
            for (int d = 1; d < 16; d <<= 1) sum += __shfl_xor(sum, d, 16);
            const float inv = 1.0f / sum;
#pragma unroll
            for (int nt = 0; nt < 4; ++nt)
                sP[m * SP_STRIDE + nt * 16 + l15] = f2bf(pr[nt] * inv);
        }
    }
    __syncthreads();

    // ---------- Phase 3: O = P V ----------
    f32x4 accO[4][2];
    {
        f32x4 zf = {0.f, 0.f, 0.f, 0.f};
#pragma unroll
        for (int mt = 0; mt < 4; ++mt)
#pragma unroll
            for (int nt = 0; nt < 2; ++nt) accO[mt][nt] = zf;
    }
#pragma unroll
    for (int kb = 0; kb < 2; ++kb) {  // K = 64 (49 padded; P cols >= 49 are exact 0)
        const int k0 = kb * 32 + q8;
        bf16x8 ap[4], bvf[2];
#pragma unroll
        for (int mt = 0; mt < 4; ++mt)
            ap[mt] = *(const bf16x8*)(sP + (mt * 16 + l15) * SP_STRIDE + k0);
#pragma unroll
        for (int nt = 0; nt < 2; ++nt)
            bvf[nt] = *(const bf16x8*)(sVt + (nt * 16 + l15) * SVT_STRIDE + k0);
#pragma unroll
        for (int mt = 0; mt < 4; ++mt)
#pragma unroll
            for (int nt = 0; nt < 2; ++nt)
                accO[mt][nt] = __builtin_amdgcn_mfma_f32_16x16x32_bf16(ap[mt], bvf[nt], accO[mt][nt], 0, 0, 0);
    }
    unsigned short* sO = sX;  // reuse x staging buffer (barrier-separated)
#pragma unroll
    for (int nt = 0; nt < 2; ++nt)
#pragma unroll
        for (int mt = 0; mt < 4; ++mt)
#pragma unroll
            for (int r = 0; r < 4; ++r)
                sO[(mt * 16 + q4 + r) * SX_STRIDE + wv * HD + nt * 16 + l15] =
                    f2bf(accO[mt][nt][r]);
    __syncthreads();

    // ---------- Phase 4: out = O @ proj_w + proj_b ----------
    f32x4 accF[4][2];
    {
        f32x4 zf = {0.f, 0.f, 0.f, 0.f};
#pragma unroll
        for (int mt = 0; mt < 4; ++mt)
#pragma unroll
            for (int nt = 0; nt < 2; ++nt) accF[mt][nt] = zf;
    }
#pragma unroll
    for (int kb = 0; kb < 6; ++kb) {
        const int k0 = kb * 32 + q8;
        bf16x8 ao[4], bwf[2];
#pragma unroll
        for (int mt = 0; mt < 4; ++mt)
            ao[mt] = *(const bf16x8*)(sO + (mt * 16 + l15) * SX_STRIDE + k0);
#pragma unroll
        for (int nt = 0; nt < 2; ++nt) {
            const int n = wv * 32 + nt * 16 + l15;
            bwf[nt] = *(const bf16x8*)(WtProj + (size_t)n * DIM + k0);
        }
#pragma unroll
        for (int mt = 0; mt < 4; ++mt)
#pragma unroll
            for (int nt = 0; nt < 2; ++nt)
                accF[mt][nt] = __builtin_amdgcn_mfma_f32_16x16x32_bf16(ao[mt], bwf[nt], accF[mt][nt], 0, 0, 0);
    }
    if (is_fp32) {
        float* outw = (float*)Out + (size_t)bw * (NTOK * DIM);
#pragma unroll
        for (int nt = 0; nt < 2; ++nt) {
            const int c = wv * 32 + nt * 16 + l15;
            const float pb = fProjB[c];
#pragma unroll
            for (int mt = 0; mt < 4; ++mt)
#pragma unroll
                for (int r = 0; r < 4; ++r) {
                    const int m = mt * 16 + q4 + r;
                    if (m < NTOK) outw[m * DIM + c] = accF[mt][nt][r] + pb;
                }
        }
    } else {
        unsigned short* outw = (unsigned short*)Out + (size_t)bw * (NTOK * DIM);
#pragma unroll
        for (int nt = 0; nt < 2; ++nt) {
            const int c = wv * 32 + nt * 16 + l15;
            const float pb = fProjB[c];
#pragma unroll
            for (int mt = 0; mt < 4; ++mt)
#pragma unroll
                for (int r = 0; r < 4; ++r) {
                    const int m = mt * 16 + q4 + r;
                    if (m < NTOK) outw[m * DIM + c] = f2bf(accF[mt][nt][r] + pb);
                }
        }
    }
}

extern "C" void kernel_launch(void* const* d_in, const int* in_sizes, int n_in,
                              void* d_out, int out_size, void* d_ws, size_t ws_size,
                              hipStream_t stream) {
    const void* x = d_in[0];
    const void* qkv_w = d_in[1];
    const void* qkv_b = d_in[2];
    const void* proj_w = d_in[3];
    const void* proj_b = d_in[4];
    const void* bias_table = d_in[5];
    const int* rel_idx = (const int*)d_in[6];

    const int nwin = in_sizes[0] / (NTOK * DIM);  // 4096
    char* ws = (char*)d_ws;

    detect_dtype<<<1, 64, 0, stream>>>((const unsigned short*)x, (int*)(ws + WS_FLAG_OFF));
    {
        const int tot = 110592 + 36864 + 576 + 192 + 1014;  // 149238
        prep_params<<<(tot + 255) / 256, 256, 0, stream>>>(qkv_w, proj_w, qkv_b, proj_b,
                                                           bias_table, ws);
    }
    win_attn_fused<<<nwin, 384, SMEM_BYTES, stream>>>(x, rel_idx, ws, d_out);
}